// Round 5
// baseline (30.196 us; speedup 1.0000x reference)
//
#include <hip/hip_runtime.h>
#include <math.h>

#define H 768
#define ISZ 512
#define IN1 513   // I+1
#define NARM 32
#define NU_C 0.1f

// U region offsets (elements)
#define U_WIH 0
#define U_WHH (3072*513)                 // 1575936
#define U_BIH (U_WHH + 3072*768)         // 3935232
#define U_BHH (U_BIH + 3072)             // 3938304
#define U_FCW (U_BHH + 3072)             // 3941376
#define U_FCB (U_FCW + 32*768)           // 3965952

// out offsets (elements)
#define O_SELR 0
#define O_PROB 1
#define O_SELA 33
#define O_HN   34
#define O_CN   (34+768)
#define O_U    (34+768+768)   // 1570

// ws layout (float units)
#define W_D    0        // 4*768 D factors (gate-major)
#define W_HN   3072     // 768 h_new
#define W_HZ   3840     // int: 1 if h0 has any nonzero
#define W_SEL  3841     // int: selected arm
#define W_PART 4096     // 96 columns x 768 (transposed partials: [m*32+a]*768 + j)

#define NPREPB 768
#define NK1B   960      // 768 prep + 192 pure-copy
#define WHH_F4 589824   // 3072*768/4

__device__ inline float wave_reduce(float v) {
    for (int d = 32; d > 0; d >>= 1) v += __shfl_xor(v, d, 64);
    return v;
}

__device__ inline float frcp(float x) { return __builtin_amdgcn_rcpf(x); }

__device__ inline void store_f4_as_2xf2(float* p, float4 v) {
    *(float2*)p = make_float2(v.x, v.y);
    *(float2*)(p + 2) = make_float2(v.z, v.w);
}

// K1: blocks [0,768): prep for j = blockIdx (4 waves; wave g handles gate row
//     g*768+j GEMV + rowsum row g*768+j), then wave 0 computes D/T/wsum/hn and
//     the per-arm (r,s,q) contributions of this j (transposed store).
//     All 960 blocks then grid-stride copy U_WHH -> out when h0 == 0.
__global__ __launch_bounds__(256) void k1_prep(
    const float* __restrict__ x, const float* __restrict__ prevr,
    const float* __restrict__ h0, const float* __restrict__ c0,
    const float* __restrict__ Wih, const float* __restrict__ Whh,
    const float* __restrict__ bih, const float* __restrict__ bhh,
    const float* __restrict__ fcW, const float* __restrict__ fcb,
    const float* __restrict__ U,
    float* __restrict__ out, float* __restrict__ ws)
{
    const int t = threadIdx.x;
    const int wave = t >> 6;
    const int lane = t & 63;

    // every block: load h0 (768 floats) as float4, detect nonzero
    float4 hv4[3];
    bool nzb = false;
    #pragma unroll
    for (int it = 0; it < 3; ++it) {
        hv4[it] = *(const float4*)(h0 + lane * 4 + it * 256);
        nzb |= (hv4[it].x != 0.f) || (hv4[it].y != 0.f) ||
               (hv4[it].z != 0.f) || (hv4[it].w != 0.f);
    }
    const bool hnz = (__ballot(nzb) != 0ull);
    if (blockIdx.x == 0 && t == 0) ((int*)ws)[W_HZ] = hnz ? 1 : 0;

    const int j = blockIdx.x;
    if (j < NPREPB) {
        const float pr = prevr[0];
        const int r = wave * H + j;
        const float* wr = Wih + (size_t)r * IN1;
        const float* ur = U + U_WIH + (size_t)r * IN1;
        float a = 0.f, tt = 0.f;
        for (int k = lane; k < IN1; k += 64) {
            float xv = (k < ISZ) ? x[k] : pr;
            a  += wr[k] * xv;
            tt += xv * xv * frcp(ur[k]);
        }
        if (hnz) {
            const float* sr = Whh + (size_t)r * H;
            const float* vr = U + U_WHH + (size_t)r * H;
            #pragma unroll
            for (int it = 0; it < 3; ++it) {
                int c = lane * 4 + it * 256;
                float4 h4 = hv4[it];
                float4 w = *(const float4*)(sr + c);
                float4 u = *(const float4*)(vr + c);
                a  += w.x*h4.x + w.y*h4.y + w.z*h4.z + w.w*h4.w;
                tt += h4.x*h4.x*frcp(u.x) + h4.y*h4.y*frcp(u.y)
                    + h4.z*h4.z*frcp(u.z) + h4.w*h4.w*frcp(u.w);
            }
        }
        a  = wave_reduce(a);
        tt = wave_reduce(tt);
        __shared__ float sa[4], st[4];
        if (lane == 0) {
            sa[wave] = a + bih[r] + bhh[r];
            st[wave] = tt + frcp(U[U_BIH + r]) + frcp(U[U_BHH + r]);
        }
        __syncthreads();
        if (wave == 0) {
            float zi = sa[0], zf = sa[1], zg = sa[2], zo = sa[3];
            float ig = 1.f / (1.f + expf(-zi));
            float fg = 1.f / (1.f + expf(-zf));
            float gg = tanhf(zg);
            float og = 1.f / (1.f + expf(-zo));
            float cj = c0[j];
            float cn = fg * cj + ig * gg;
            float th = tanhf(cn);
            float hn = og * th;
            float dtc = og * (1.f - th * th);
            float D0 = dtc * gg * ig * (1.f - ig);
            float D1 = dtc * cj * fg * (1.f - fg);
            float D2 = dtc * ig * (1.f - gg * gg);
            float D3 = th * og * (1.f - og);
            float wsum = D0*D0*st[0] + D1*D1*st[1] + D2*D2*st[2] + D3*D3*st[3];
            if (lane == 0) {
                ws[W_D + 0*H + j] = D0;
                ws[W_D + 1*H + j] = D1;
                ws[W_D + 2*H + j] = D2;
                ws[W_D + 3*H + j] = D3;
                ws[W_HN + j] = hn;
                out[O_HN + j] = hn;
                out[O_CN + j] = cn;
            }
            if (lane < NARM) {
                float fw = fcW[(size_t)lane * H + j];
                float uf = U[U_FCW + (size_t)lane * H + j];
                float rc = fw * hn;
                float sc = fw * fw * wsum;
                float qc = hn * hn * frcp(uf);
                if (j == 0) {
                    rc += fcb[lane];
                    qc += frcp(U[U_FCB + lane]);
                }
                ws[W_PART + (size_t)(     lane) * NPREPB + j] = rc;
                ws[W_PART + (size_t)(32 + lane) * NPREPB + j] = sc;
                ws[W_PART + (size_t)(64 + lane) * NPREPB + j] = qc;
            }
        }
    }

    // grid-stride copy of U_WHH (valid only when h0 == 0; else K3 handles it)
    if (!hnz) {
        const float4* src = (const float4*)(U + U_WHH);
        float* dst = out + O_U + U_WHH;
        for (int i = blockIdx.x * 256 + t; i < WHH_F4; i += NK1B * 256) {
            float4 v = src[i];
            store_f4_as_2xf2(dst + (size_t)i * 4, v);
        }
    }
}

// K2: 1 block x 256: reduce 96x768 transposed partials (two half-sums in
// parallel), UCB select, softmax, outputs.
__global__ __launch_bounds__(256) void k2_select(
    float* __restrict__ out, float* __restrict__ ws)
{
    __shared__ float red2[2][96];
    int t = threadIdx.x;
    int half = t >> 7;          // 0 or 1
    int c = t & 127;
    if (c < 96) {
        const float4* col = (const float4*)(ws + W_PART + (size_t)c * NPREPB
                                            + half * (NPREPB / 2));
        float4 s4 = make_float4(0.f, 0.f, 0.f, 0.f);
        #pragma unroll 8
        for (int i = 0; i < NPREPB / 8; ++i) {   // 96 float4 per half
            float4 v = col[i];
            s4.x += v.x; s4.y += v.y; s4.z += v.z; s4.w += v.w;
        }
        red2[half][c] = (s4.x + s4.y) + (s4.z + s4.w);
    }
    __syncthreads();
    if (t < NARM) {
        float r = red2[0][t]      + red2[1][t];
        float s = red2[0][32 + t] + red2[1][32 + t];
        float q = red2[0][64 + t] + red2[1][64 + t];
        // inclusive prefix sum of q across 32 lanes
        float cum = q;
        for (int d = 1; d < 32; d <<= 1) {
            float v = __shfl_up(cum, d, 32);
            if (t >= d) cum += v;
        }
        float sc = r + NU_C * sqrtf(s + cum);
        // argmax (first max wins ties)
        float best = sc; int sel = t;
        for (int d = 16; d > 0; d >>= 1) {
            float ob = __shfl_xor(best, d, 32);
            int   oi = __shfl_xor(sel, d, 32);
            if (ob > best || (ob == best && oi < sel)) { best = ob; sel = oi; }
        }
        // softmax over r
        float mx = r;
        for (int d = 16; d > 0; d >>= 1) mx = fmaxf(mx, __shfl_xor(mx, d, 32));
        float e = expf(r - mx);
        float se = e;
        for (int d = 16; d > 0; d >>= 1) se += __shfl_xor(se, d, 32);
        out[O_PROB + t] = e / se;
        float rsel = __shfl(r, sel, 32);
        if (t == 0) {
            out[O_SELR] = rsel;
            out[O_SELA] = (float)sel;
            ((int*)ws)[W_SEL] = sel;
        }
    }
}

// K3: sel-dependent U_new regions. W_hh only when h0 != 0.
// grid: [0,3072) W_ih rows | [3072,5376) W_hh f4 | 6 bias | 24 fcW | 1 fcb
#define B_A 3072
#define B_B (B_A + 2304)
#define B_C (B_B + 6)
#define B_D (B_C + 24)
__global__ __launch_bounds__(256) void k3_unew(
    const float* __restrict__ x, const float* __restrict__ prevr,
    const float* __restrict__ h0, const float* __restrict__ fcW,
    const float* __restrict__ U, float* __restrict__ out,
    const float* __restrict__ ws)
{
    const int sel = ((const int*)ws)[W_SEL];
    int b = blockIdx.x, t = threadIdx.x;
    float* Un = out + O_U;
    if (b < B_A) {                 // W_ih rows, one row per block (513 elems)
        int g = b / H, j = b - g * H;
        float s = fcW[(size_t)sel * H + j] * ws[W_D + g*H + j];
        float s2 = s * s;
        const float* u = U + U_WIH + (size_t)b * IN1;
        float* o = Un + U_WIH + (size_t)b * IN1;
        float xv1 = x[t];
        float xv2 = x[t + 256];
        o[t]       = u[t]       + s2 * xv1 * xv1;
        o[t + 256] = u[t + 256] + s2 * xv2 * xv2;
        if (t == 0) {
            float pr = prevr[0];
            o[512] = u[512] + s2 * pr * pr;
        }
    } else if (b < B_B) {          // W_hh flat float4 (skip if copied by K1)
        const int hz = ((const int*)ws)[W_HZ];
        if (!hz) return;
        int e = ((b - B_A) * 256 + t) * 4;   // < 2359296
        float4 u4 = *(const float4*)(U + U_WHH + e);
        int r = e / H;
        int g = r / H, j = r - g * H;
        int k = e - r * H;
        float s = fcW[(size_t)sel * H + j] * ws[W_D + g*H + j];
        float s2 = s * s;
        float4 h4 = *(const float4*)(h0 + k);
        float4 o4;
        o4.x = u4.x + s2 * h4.x * h4.x;
        o4.y = u4.y + s2 * h4.y * h4.y;
        o4.z = u4.z + s2 * h4.z * h4.z;
        o4.w = u4.w + s2 * h4.w * h4.w;
        store_f4_as_2xf2(Un + U_WHH + e, o4);
    } else if (b < B_C) {          // biases: 6144 elems, float4
        int m = ((b - B_B) * 256 + t) * 4;
        int r = (m < 3072) ? m : m - 3072;
        int g = r / H, j = r - g * H;
        float4 f4 = *(const float4*)(fcW + (size_t)sel * H + j);
        float4 d4 = *(const float4*)(ws + W_D + g*H + j);
        float4 u4 = *(const float4*)(U + U_BIH + m);
        float4 o4;
        float sx = f4.x*d4.x, sy = f4.y*d4.y, sz = f4.z*d4.z, sw = f4.w*d4.w;
        o4.x = u4.x + sx*sx; o4.y = u4.y + sy*sy;
        o4.z = u4.z + sz*sz; o4.w = u4.w + sw*sw;
        store_f4_as_2xf2(Un + U_BIH + m, o4);
    } else if (b < B_D) {          // fc_W: 24576 elems, float4
        int e = ((b - B_C) * 256 + t) * 4;
        int a = e / H, j = e - a * H;
        float4 h4 = *(const float4*)(ws + W_HN + j);
        float4 u4 = *(const float4*)(U + U_FCW + e);
        float m = (a <= sel) ? 1.f : 0.f;
        float4 o4;
        o4.x = u4.x + m * h4.x * h4.x;
        o4.y = u4.y + m * h4.y * h4.y;
        o4.z = u4.z + m * h4.z * h4.z;
        o4.w = u4.w + m * h4.w * h4.w;
        store_f4_as_2xf2(Un + U_FCW + e, o4);
    } else {                       // fc_b
        if (t < NARM)
            Un[U_FCB + t] = U[U_FCB + t] + ((t <= sel) ? 1.f : 0.f);
    }
}

extern "C" void kernel_launch(void* const* d_in, const int* in_sizes, int n_in,
                              void* d_out, int out_size, void* d_ws, size_t ws_size,
                              hipStream_t stream) {
    const float* x     = (const float*)d_in[0];
    const float* prevr = (const float*)d_in[1];
    const float* h0    = (const float*)d_in[2];
    const float* c0    = (const float*)d_in[3];
    const float* Wih   = (const float*)d_in[4];
    const float* Whh   = (const float*)d_in[5];
    const float* bih   = (const float*)d_in[6];
    const float* bhh   = (const float*)d_in[7];
    const float* fcW   = (const float*)d_in[8];
    const float* fcb   = (const float*)d_in[9];
    const float* U     = (const float*)d_in[10];
    float* out = (float*)d_out;
    float* ws  = (float*)d_ws;

    hipLaunchKernelGGL(k1_prep, dim3(NK1B), dim3(256), 0, stream,
                       x, prevr, h0, c0, Wih, Whh, bih, bhh, fcW, fcb, U, out, ws);
    hipLaunchKernelGGL(k2_select, dim3(1), dim3(256), 0, stream,
                       out, ws);
    hipLaunchKernelGGL(k3_unew, dim3(B_D + 1), dim3(256), 0, stream,
                       x, prevr, h0, fcW, U, out, ws);
}